// Round 9
// baseline (65.648 us; speedup 1.0000x reference)
//
#include <hip/hip_runtime.h>

typedef __attribute__((ext_vector_type(8))) short bf16x8;
typedef __attribute__((ext_vector_type(4))) float f32x4;
typedef __attribute__((ext_vector_type(8))) unsigned short u16x8;

__device__ __forceinline__ unsigned short f2bf(float f) {
  union { float f; unsigned u; } v; v.f = f;
  unsigned r = v.u + 0x7FFF + ((v.u >> 16) & 1);
  return (unsigned short)(r >> 16);
}
__device__ __forceinline__ float bf2f(unsigned short s) {
  union { unsigned u; float f; } v; v.u = ((unsigned)s) << 16;
  return v.f;
}
__device__ __forceinline__ void gll16(const unsigned short* g, unsigned short* l) {
  __builtin_amdgcn_global_load_lds(
      (const __attribute__((address_space(1))) void*)g,
      (__attribute__((address_space(3))) void*)l, 16, 0, 0);
}

// W[m][n][k] f32 -> Wt[m][k][n] bf16, 16B-chunk XOR swizzle: slot = g ^ (k&7)
__global__ __launch_bounds__(256) void transpose_w(const float* __restrict__ W1,
                                                   const float* __restrict__ W2,
                                                   unsigned short* __restrict__ W1t,
                                                   unsigned short* __restrict__ W2t) {
  __shared__ float ws_[64 * 64];
  const int m = blockIdx.x & 63, sel = blockIdx.x >> 6;
  const float* src = (sel ? W2 : W1) + m * 4096;
  unsigned short* dst = (sel ? W2t : W1t) + m * 4096;
  const int t = threadIdx.x;
  #pragma unroll
  for (int i = 0; i < 4; ++i) {
    const int idx = i * 256 + t;
    *(float4*)&ws_[idx << 2] = *(const float4*)&src[idx << 2];
  }
  __syncthreads();
  #pragma unroll
  for (int j = 0; j < 2; ++j) {
    const int idx = j * 256 + t;
    const int k = idx >> 3, g = idx & 7;
    u16x8 o;
    #pragma unroll
    for (int jj = 0; jj < 8; ++jj) o[jj] = f2bf(ws_[(((g << 3) + jj) << 6) + k]);
    const int slot = g ^ (k & 7);
    *(u16x8*)&dst[(k << 6) + (slot << 3)] = o;
  }
}

// One layer: stream 16 W-chunks (32KB = 4 m-slices) through 3 LDS buffers,
// distance-2 prefetch, per-block staggered chunk order (cc = (c+phase)&15).
// Per iter: issue c+2 -> compute c -> s_waitcnt vmcnt(4) [c+1 landed; per-wave
// wait + s_barrier => block-wide] -> s_barrier. Buf (c+2)%3 overwrite is safe:
// its readers (chunk c-1) passed the previous barrier. Tail: iter13 wait leaves
// {c14,c15}<=4 so c14 landed; iter14 does vmcnt(0) for c15.
__device__ __forceinline__ void layer_pass(
    const unsigned short* __restrict__ Wt, unsigned short* wbuf,
    const unsigned short* u_lds, const bf16x8 (&Bf)[4][2],
    f32x4 (&acc)[4], int phase, int aoff0, int aoff1, int ubase, int t) {
  #pragma unroll
  for (int dt = 0; dt < 4; ++dt) acc[dt] = (f32x4){0.f, 0.f, 0.f, 0.f};

  // prologue: issue chunks 0,1 (staggered)
  {
    const unsigned short* s0 = Wt + ((phase) & 15) * 16384;
    const unsigned short* s1 = Wt + ((phase + 1) & 15) * 16384;
    #pragma unroll
    for (int j = 0; j < 4; ++j) gll16(s0 + j * 4096 + t * 8, wbuf + j * 4096 + t * 8);
    #pragma unroll
    for (int j = 0; j < 4; ++j) gll16(s1 + j * 4096 + t * 8, wbuf + 16384 + j * 4096 + t * 8);
  }
  __builtin_amdgcn_sched_barrier(0);
  asm volatile("s_waitcnt vmcnt(4) lgkmcnt(0)" ::: "memory");
  __builtin_amdgcn_sched_barrier(0);
  __builtin_amdgcn_s_barrier();
  __builtin_amdgcn_sched_barrier(0);

  int rdsel = 0;
  for (int c = 0; c < 14; ++c) {
    // issue chunk c+2 into buf (rdsel+2)%3
    {
      const int stsel = rdsel == 0 ? 2 : rdsel - 1;  // (rdsel+2)%3
      const unsigned short* wsrc = Wt + (((c + 2 + phase) & 15) * 16384);
      unsigned short* dst = wbuf + stsel * 16384;
      #pragma unroll
      for (int j = 0; j < 4; ++j) gll16(wsrc + j * 4096 + t * 8, dst + j * 4096 + t * 8);
    }
    const unsigned short* bufc = wbuf + rdsel * 16384;
    const int cc = (c + phase) & 15;
    #pragma unroll
    for (int mm = 0; mm < 4; ++mm) {
      const int m = (cc << 2) + mm;
      bf16x8 a0 = *(const bf16x8*)(bufc + mm * 4096 + aoff0);
      bf16x8 a1 = *(const bf16x8*)(bufc + mm * 4096 + aoff1);
      #pragma unroll
      for (int dt = 0; dt < 4; ++dt) {
        f32x4 tt = {0.f, 0.f, 0.f, 0.f};
        tt = __builtin_amdgcn_mfma_f32_16x16x32_bf16(a0, Bf[dt][0], tt, 0, 0, 0);
        tt = __builtin_amdgcn_mfma_f32_16x16x32_bf16(a1, Bf[dt][1], tt, 0, 0, 0);
        const float uu = bf2f(u_lds[m * 128 + ubase + dt * 16]);
        #pragma unroll
        for (int r = 0; r < 4; ++r) acc[dt][r] += uu * tt[r];
      }
    }
    __builtin_amdgcn_sched_barrier(0);
    asm volatile("s_waitcnt vmcnt(4)" ::: "memory");
    __builtin_amdgcn_sched_barrier(0);
    __builtin_amdgcn_s_barrier();
    __builtin_amdgcn_sched_barrier(0);
    rdsel = rdsel == 2 ? 0 : rdsel + 1;
  }
  // iters 14, 15 (no more issues)
  #pragma unroll
  for (int c = 14; c < 16; ++c) {
    const unsigned short* bufc = wbuf + rdsel * 16384;
    const int cc = (c + phase) & 15;
    #pragma unroll
    for (int mm = 0; mm < 4; ++mm) {
      const int m = (cc << 2) + mm;
      bf16x8 a0 = *(const bf16x8*)(bufc + mm * 4096 + aoff0);
      bf16x8 a1 = *(const bf16x8*)(bufc + mm * 4096 + aoff1);
      #pragma unroll
      for (int dt = 0; dt < 4; ++dt) {
        f32x4 tt = {0.f, 0.f, 0.f, 0.f};
        tt = __builtin_amdgcn_mfma_f32_16x16x32_bf16(a0, Bf[dt][0], tt, 0, 0, 0);
        tt = __builtin_amdgcn_mfma_f32_16x16x32_bf16(a1, Bf[dt][1], tt, 0, 0, 0);
        const float uu = bf2f(u_lds[m * 128 + ubase + dt * 16]);
        #pragma unroll
        for (int r = 0; r < 4; ++r) acc[dt][r] += uu * tt[r];
      }
    }
    if (c == 14) {
      __builtin_amdgcn_sched_barrier(0);
      asm volatile("s_waitcnt vmcnt(0)" ::: "memory");  // chunk 15 lands
      __builtin_amdgcn_sched_barrier(0);
      __builtin_amdgcn_s_barrier();
      __builtin_amdgcn_sched_barrier(0);
    }
    rdsel = rdsel == 2 ? 0 : rdsel + 1;
  }
  __syncthreads();  // all waves done with wbuf + u_lds before epilogue rewrites
}

// Fused cross layers. Block = (b, 128-d tile); 128 blocks, 512 threads
// = 8 waves = 4 kt x 2 dh (each wave: 16 k x 64 d via 4 dt fragments).
// XCD swizzle: id%8 = b%8 (x[b] shared in one XCD's L2).
// Dynamic LDS 112KB: wbuf[3][32KB] | u_lds[64][128] bf16 (16KB)
__global__ __launch_bounds__(512) void fused_layers(
    const float* __restrict__ x,
    const unsigned short* __restrict__ W1t, const unsigned short* __restrict__ W2t,
    unsigned short* __restrict__ X1kd, unsigned short* __restrict__ X2kd) {
  extern __shared__ char smem[];
  unsigned short* wbuf = (unsigned short*)smem;              // 3*16384 shorts
  unsigned short* u_lds = (unsigned short*)(smem + 98304);   // 8192 shorts

  const int t = threadIdx.x;
  const int l = t & 63, w = t >> 6;
  const int kt = w & 3, dh = w >> 2;
  const int id = blockIdx.x;
  const int rest = id >> 3;
  const int dtile = rest & 3;
  const int b = ((rest >> 2) << 3) | (id & 7);
  const int d0 = dtile << 7;
  const int phase = rest & 15;
  const int l15 = l & 15, lg = l >> 4;

  // stage u1 = x[b, m, d-tile] -> u_lds[m][128] bf16 (16 cols per thread)
  {
    const int m = t >> 3, ch = t & 7;
    const float* src = x + ((b << 6) + m) * 512 + d0 + (ch << 4);
    u16x8 o0, o1;
    #pragma unroll
    for (int jj = 0; jj < 8; ++jj) o0[jj] = f2bf(src[jj]);
    #pragma unroll
    for (int jj = 0; jj < 8; ++jj) o1[jj] = f2bf(src[8 + jj]);
    *(u16x8*)&u_lds[(m << 7) + (ch << 4)] = o0;
    *(u16x8*)&u_lds[(m << 7) + (ch << 4) + 8] = o1;
  }

  // B fragments from x (V = X0 both layers): Bf[dt][h][jj] = x[b, h*32+lg*8+jj, dcol]
  bf16x8 Bf[4][2];
  {
    const float* xb = x + (b << 6) * 512 + d0 + dh * 64 + l15;
    #pragma unroll
    for (int dt = 0; dt < 4; ++dt)
      #pragma unroll
      for (int h = 0; h < 2; ++h) {
        bf16x8 o;
        #pragma unroll
        for (int jj = 0; jj < 8; ++jj)
          o[jj] = (short)f2bf(xb[(h * 32 + lg * 8 + jj) * 512 + dt * 16]);
        Bf[dt][h] = o;
      }
  }

  const int krow = kt * 16 + l15;
  const int kx = krow & 7;
  const int aoff0 = krow * 64 + ((0 + lg) ^ kx) * 8;
  const int aoff1 = krow * 64 + ((4 + lg) ^ kx) * 8;
  const int ubase = dh * 64 + l15;

  f32x4 acc[4];

  // ---- layer 1 ----
  layer_pass(W1t, wbuf, u_lds, Bf, acc, phase, aoff0, aoff1, ubase, t);

  // epilogue 1: relu -> X1kd (global) AND u_lds (layer-2 u). layer_pass ended
  // with __syncthreads(); disjoint slots per lane.
  #pragma unroll
  for (int dt = 0; dt < 4; ++dt) {
    #pragma unroll
    for (int r = 0; r < 4; ++r) {
      const int k = kt * 16 + lg * 4 + r;
      const int dl = dh * 64 + dt * 16 + l15;
      const unsigned short hv = f2bf(fmaxf(acc[dt][r], 0.f));
      X1kd[((b << 6) + k) * 512 + d0 + dl] = hv;
      u_lds[k * 128 + dl] = hv;
    }
  }
  // layer-2 prologue waits vmcnt(4) lgkmcnt(0) + barrier: drains the 16 stores
  // (older than chunk1) and makes u_lds writes visible.

  // ---- layer 2 ----
  layer_pass(W2t, wbuf, u_lds, Bf, acc, phase, aoff0, aoff1, ubase, t);

  // epilogue 2
  #pragma unroll
  for (int dt = 0; dt < 4; ++dt) {
    #pragma unroll
    for (int r = 0; r < 4; ++r) {
      const int k = kt * 16 + lg * 4 + r;
      const int dl = dh * 64 + dt * 16 + l15;
      X2kd[((b << 6) + k) * 512 + d0 + dl] = f2bf(fmaxf(acc[dt][r], 0.f));
    }
  }
}

// out[b,p,d] = LN_d( x[b,p,d] + pb[p] + sum_t pw[p,t]*X1kd[b][t][d] + pw[p,64+t]*X2kd[b][t][d] )
// grid 256 = (b, 8-p group); 512 threads = d.
__global__ __launch_bounds__(512) void proj_ln(
    const float* __restrict__ x, const unsigned short* __restrict__ X1kd,
    const unsigned short* __restrict__ X2kd, const float* __restrict__ pw,
    const float* __restrict__ pb, const float* __restrict__ gamma,
    const float* __restrict__ beta, float* __restrict__ out) {
  const int b = blockIdx.x >> 3, pg = blockIdx.x & 7;
  const int d = threadIdx.x;
  __shared__ float red[8 * 16];

  float s[8] = {0.f, 0.f, 0.f, 0.f, 0.f, 0.f, 0.f, 0.f};
  const float* pwb = pw + pg * 8 * 128;  // block-uniform rows
  const unsigned short* r1 = X1kd + (b << 6) * 512 + d;
  const unsigned short* r2 = X2kd + (b << 6) * 512 + d;

  #pragma unroll 4
  for (int tt = 0; tt < 64; ++tt) {
    const float c = bf2f(r1[tt * 512]);
    #pragma unroll
    for (int pi = 0; pi < 8; ++pi) s[pi] += pwb[pi * 128 + tt] * c;
  }
  #pragma unroll 4
  for (int tt = 0; tt < 64; ++tt) {
    const float c = bf2f(r2[tt * 512]);
    #pragma unroll
    for (int pi = 0; pi < 8; ++pi) s[pi] += pwb[pi * 128 + 64 + tt] * c;
  }

  const int wv = d >> 6, ln = d & 63;
  float yv[8];
  #pragma unroll
  for (int pi = 0; pi < 8; ++pi) {
    const int p = pg * 8 + pi;
    const float y = x[((b << 6) + p) * 512 + d] + pb[p] + s[pi];
    yv[pi] = y;
    float sm = y, sq = y * y;
    #pragma unroll
    for (int off = 32; off > 0; off >>= 1) {
      sm += __shfl_xor(sm, off);
      sq += __shfl_xor(sq, off);
    }
    if (ln == 0) { red[pi * 16 + wv] = sm; red[pi * 16 + 8 + wv] = sq; }
  }
  __syncthreads();

  const float gam = gamma[d], bet = beta[d];
  #pragma unroll
  for (int pi = 0; pi < 8; ++pi) {
    float sum = 0.f, sumsq = 0.f;
    #pragma unroll
    for (int j = 0; j < 8; ++j) { sum += red[pi * 16 + j]; sumsq += red[pi * 16 + 8 + j]; }
    const float mu = sum * (1.f / 512.f);
    const float var = sumsq * (1.f / 512.f) - mu * mu;
    const float rs = rsqrtf(var + 1e-5f);
    const int p = pg * 8 + pi;
    out[((b << 6) + p) * 512 + d] = gam * (yv[pi] - mu) * rs + bet;
  }
}

extern "C" void kernel_launch(void* const* d_in, const int* in_sizes, int n_in,
                              void* d_out, int out_size, void* d_ws, size_t ws_size,
                              hipStream_t stream) {
  const float* x     = (const float*)d_in[0];
  const float* W1    = (const float*)d_in[1];
  const float* W2    = (const float*)d_in[2];
  const float* pw    = (const float*)d_in[3];
  const float* pb    = (const float*)d_in[4];
  const float* gamma = (const float*)d_in[5];
  const float* beta  = (const float*)d_in[6];
  float* out = (float*)d_out;

  char* ws = (char*)d_ws;
  unsigned short* X1kd = (unsigned short*)(ws);                          // 2MB [32][64][512]
  unsigned short* X2kd = (unsigned short*)(ws + (2u << 20));             // 2MB [32][64][512]
  unsigned short* W1t  = (unsigned short*)(ws + (4u << 20));             // 512KB swz
  unsigned short* W2t  = (unsigned short*)(ws + (4u << 20) + (512u << 10));

  transpose_w<<<dim3(128), dim3(256), 0, stream>>>(W1, W2, W1t, W2t);
  fused_layers<<<dim3(128), dim3(512), 114688, stream>>>(x, W1t, W2t, X1kd, X2kd);
  proj_ln<<<dim3(256), dim3(512), 0, stream>>>(x, X1kd, X2kd, pw, pb, gamma, beta, out);
}

// Round 11
// 55.706 us; speedup vs baseline: 1.1785x; 1.1785x over previous
//
#include <hip/hip_runtime.h>

typedef __attribute__((ext_vector_type(8))) short bf16x8;
typedef __attribute__((ext_vector_type(4))) float f32x4;
typedef __attribute__((ext_vector_type(8))) unsigned short u16x8;

__device__ __forceinline__ unsigned short f2bf(float f) {
  union { float f; unsigned u; } v; v.f = f;
  unsigned r = v.u + 0x7FFF + ((v.u >> 16) & 1);
  return (unsigned short)(r >> 16);
}
__device__ __forceinline__ float bf2f(unsigned short s) {
  union { unsigned u; float f; } v; v.u = ((unsigned)s) << 16;
  return v.f;
}
__device__ __forceinline__ void gll16(const unsigned short* g, unsigned short* l) {
  __builtin_amdgcn_global_load_lds(
      (const __attribute__((address_space(1))) void*)g,
      (__attribute__((address_space(3))) void*)l, 16, 0, 0);
}

// W[m][n][k] f32 -> Wt[m][k][n] bf16, 16B-chunk XOR swizzle: slot = g ^ (k&7)
__global__ __launch_bounds__(256) void transpose_w(const float* __restrict__ W1,
                                                   const float* __restrict__ W2,
                                                   unsigned short* __restrict__ W1t,
                                                   unsigned short* __restrict__ W2t) {
  __shared__ float ws_[64 * 64];
  const int m = blockIdx.x & 63, sel = blockIdx.x >> 6;
  const float* src = (sel ? W2 : W1) + m * 4096;
  unsigned short* dst = (sel ? W2t : W1t) + m * 4096;
  const int t = threadIdx.x;
  #pragma unroll
  for (int i = 0; i < 4; ++i) {
    const int idx = i * 256 + t;
    *(float4*)&ws_[idx << 2] = *(const float4*)&src[idx << 2];
  }
  __syncthreads();
  #pragma unroll
  for (int j = 0; j < 2; ++j) {
    const int idx = j * 256 + t;
    const int k = idx >> 3, g = idx & 7;
    u16x8 o;
    #pragma unroll
    for (int jj = 0; jj < 8; ++jj) o[jj] = f2bf(ws_[(((g << 3) + jj) << 6) + k]);
    const int slot = g ^ (k & 7);
    *(u16x8*)&dst[(k << 6) + (slot << 3)] = o;
  }
}

// One layer: stream 16 W-chunks (32KB = 4 m-slices) through 3 LDS buffers,
// distance-2 prefetch, per-block STAGGERED chunk order (cc = (c+phase)&15) so
// co-resident blocks don't hammer identical L2 lines in lockstep.
// Per iter: issue c+2 -> compute c -> s_waitcnt vmcnt(4) [c+1 landed] ->
// s_barrier. Buf (c+2)%3 overwrite safe: its readers passed previous barrier.
// u_lds layout: [dl][m] with 68-short padded stride -> per-iter u read is one
// ds_read_b64 (4 m's), conflict-free.
__device__ __forceinline__ void layer_pass(
    const unsigned short* __restrict__ Wt, unsigned short* wbuf,
    const unsigned short* u_lds, const bf16x8 (&Bf)[2][2],
    f32x4& acc0, f32x4& acc1, int phase,
    int aoff0, int aoff1, int ubase0, int ubase1, int t) {
  // prologue: issue chunks phase, phase+1
  {
    const unsigned short* s0 = Wt + ((phase) & 15) * 16384;
    const unsigned short* s1 = Wt + ((phase + 1) & 15) * 16384;
    #pragma unroll
    for (int j = 0; j < 4; ++j) gll16(s0 + j * 4096 + t * 8, wbuf + j * 4096 + t * 8);
    #pragma unroll
    for (int j = 0; j < 4; ++j) gll16(s1 + j * 4096 + t * 8, wbuf + 16384 + j * 4096 + t * 8);
  }
  __builtin_amdgcn_sched_barrier(0);
  asm volatile("s_waitcnt vmcnt(4) lgkmcnt(0)" ::: "memory");
  __builtin_amdgcn_sched_barrier(0);
  __builtin_amdgcn_s_barrier();
  __builtin_amdgcn_sched_barrier(0);

  acc0 = (f32x4){0.f, 0.f, 0.f, 0.f};
  acc1 = (f32x4){0.f, 0.f, 0.f, 0.f};

  int rdsel = 0;
  for (int c = 0; c < 16; ++c) {
    if (c < 14) {  // issue chunk c+2 into buf (rdsel+2)%3
      const int stsel = rdsel == 0 ? 2 : rdsel - 1;
      const unsigned short* wsrc = Wt + (((c + 2 + phase) & 15) * 16384);
      unsigned short* dst = wbuf + stsel * 16384;
      #pragma unroll
      for (int j = 0; j < 4; ++j) gll16(wsrc + j * 4096 + t * 8, dst + j * 4096 + t * 8);
    }
    const unsigned short* bufc = wbuf + rdsel * 16384;
    const int cc = (c + phase) & 15;

    const ushort4 uq0 = *(const ushort4*)&u_lds[ubase0 + (cc << 2)];
    const ushort4 uq1 = *(const ushort4*)&u_lds[ubase1 + (cc << 2)];
    const unsigned short us0[4] = {uq0.x, uq0.y, uq0.z, uq0.w};
    const unsigned short us1[4] = {uq1.x, uq1.y, uq1.z, uq1.w};

    #pragma unroll
    for (int mm = 0; mm < 4; ++mm) {
      bf16x8 a0 = *(const bf16x8*)(bufc + mm * 4096 + aoff0);
      bf16x8 a1 = *(const bf16x8*)(bufc + mm * 4096 + aoff1);
      f32x4 t0 = {0.f, 0.f, 0.f, 0.f}, t1 = {0.f, 0.f, 0.f, 0.f};
      t0 = __builtin_amdgcn_mfma_f32_16x16x32_bf16(a0, Bf[0][0], t0, 0, 0, 0);
      t0 = __builtin_amdgcn_mfma_f32_16x16x32_bf16(a1, Bf[0][1], t0, 0, 0, 0);
      t1 = __builtin_amdgcn_mfma_f32_16x16x32_bf16(a0, Bf[1][0], t1, 0, 0, 0);
      t1 = __builtin_amdgcn_mfma_f32_16x16x32_bf16(a1, Bf[1][1], t1, 0, 0, 0);
      const float u0 = bf2f(us0[mm]);
      const float u1 = bf2f(us1[mm]);
      #pragma unroll
      for (int r = 0; r < 4; ++r) {
        acc0[r] += u0 * t0[r];
        acc1[r] += u1 * t1[r];
      }
    }
    __builtin_amdgcn_sched_barrier(0);
    if (c < 14) {
      asm volatile("s_waitcnt vmcnt(4)" ::: "memory");
    } else if (c == 14) {
      asm volatile("s_waitcnt vmcnt(0)" ::: "memory");
    }
    __builtin_amdgcn_sched_barrier(0);
    if (c < 15) {
      __builtin_amdgcn_s_barrier();
      __builtin_amdgcn_sched_barrier(0);
    }
    rdsel = rdsel == 2 ? 0 : rdsel + 1;
  }
  __syncthreads();  // all waves done with wbuf + u_lds before epilogue rewrites
}

// Fused cross layers. Block = (b, 64-d tile); 256 blocks, 512 threads
// = 8 waves = 4 kt x 2 dh. phase = b&15 staggers chunk order across
// co-resident blocks. Dynamic LDS: wbuf[3][32KB] | u_lds[64][68] = 107008 B
__global__ __launch_bounds__(512) void fused_layers(
    const float* __restrict__ x,
    const unsigned short* __restrict__ W1t, const unsigned short* __restrict__ W2t,
    unsigned short* __restrict__ X1kd, unsigned short* __restrict__ X2kd) {
  extern __shared__ char smem[];
  unsigned short* wbuf = (unsigned short*)smem;              // 3*16384 shorts
  unsigned short* u_lds = (unsigned short*)(smem + 98304);   // [dl][68]

  const int t = threadIdx.x;
  const int l = t & 63, w = t >> 6;
  const int kt = w & 3, dh = w >> 2;
  const int b = blockIdx.x >> 3, d0 = (blockIdx.x & 7) << 6;
  const int phase = b & 15;
  const int l15 = l & 15, lg = l >> 4;

  // stage u1 = bf16(x[b, m, d-tile]) -> u_lds[dl][m] (transposed, padded)
  {
    const int m = t >> 3, ch = t & 7;
    const float* src = x + ((b << 6) + m) * 512 + d0 + (ch << 3);
    #pragma unroll
    for (int jj = 0; jj < 8; ++jj)
      u_lds[((ch << 3) + jj) * 68 + m] = f2bf(src[jj]);
  }

  // B fragments from x (V = X0 both layers)
  bf16x8 Bf[2][2];
  {
    const float* xb = x + (b << 6) * 512 + d0 + dh * 32 + l15;
    #pragma unroll
    for (int dt = 0; dt < 2; ++dt)
      #pragma unroll
      for (int h = 0; h < 2; ++h) {
        bf16x8 o;
        #pragma unroll
        for (int jj = 0; jj < 8; ++jj)
          o[jj] = (short)f2bf(xb[(h * 32 + lg * 8 + jj) * 512 + dt * 16]);
        Bf[dt][h] = o;
      }
  }

  const int krow = kt * 16 + l15;
  const int kx = krow & 7;
  const int aoff0 = krow * 64 + ((0 + lg) ^ kx) * 8;
  const int aoff1 = krow * 64 + ((4 + lg) ^ kx) * 8;
  const int ubase0 = (dh * 32 + l15) * 68;
  const int ubase1 = (dh * 32 + 16 + l15) * 68;

  f32x4 acc0, acc1;

  // ---- layer 1 ----
  layer_pass(W1t, wbuf, u_lds, Bf, acc0, acc1, phase, aoff0, aoff1, ubase0, ubase1, t);

  // epilogue 1: relu -> X1kd (global) AND u_lds (layer-2 u, transposed layout).
  #pragma unroll
  for (int dt = 0; dt < 2; ++dt) {
    const f32x4 a = dt ? acc1 : acc0;
    #pragma unroll
    for (int r = 0; r < 4; ++r) {
      const int k = kt * 16 + lg * 4 + r;
      const int dl = dh * 32 + dt * 16 + l15;
      const unsigned short hv = f2bf(fmaxf(a[r], 0.f));
      X1kd[((b << 6) + k) * 512 + d0 + dl] = hv;
      u_lds[dl * 68 + k] = hv;
    }
  }
  // layer-2 prologue waits vmcnt(4) lgkmcnt(0) + barrier: drains the 16 stores
  // (older than its chunk1) and makes u_lds writes visible block-wide.

  // ---- layer 2 ----
  layer_pass(W2t, wbuf, u_lds, Bf, acc0, acc1, phase, aoff0, aoff1, ubase0, ubase1, t);

  // epilogue 2 (FIX vs R10: use a[r], not acc0[r])
  #pragma unroll
  for (int dt = 0; dt < 2; ++dt) {
    const f32x4 a = dt ? acc1 : acc0;
    #pragma unroll
    for (int r = 0; r < 4; ++r) {
      const int k = kt * 16 + lg * 4 + r;
      const int dl = dh * 32 + dt * 16 + l15;
      X2kd[((b << 6) + k) * 512 + d0 + dl] = f2bf(fmaxf(a[r], 0.f));
    }
  }
}

// out[b,p,d] = LN_d( x[b,p,d] + pb[p] + sum_t pw[p,t]*X1kd[b][t][d] + pw[p,64+t]*X2kd[b][t][d] )
// grid 256 = (b, 8-p group); 512 threads = d.
__global__ __launch_bounds__(512) void proj_ln(
    const float* __restrict__ x, const unsigned short* __restrict__ X1kd,
    const unsigned short* __restrict__ X2kd, const float* __restrict__ pw,
    const float* __restrict__ pb, const float* __restrict__ gamma,
    const float* __restrict__ beta, float* __restrict__ out) {
  const int b = blockIdx.x >> 3, pg = blockIdx.x & 7;
  const int d = threadIdx.x;
  __shared__ float red[8 * 16];

  float s[8] = {0.f, 0.f, 0.f, 0.f, 0.f, 0.f, 0.f, 0.f};
  const float* pwb = pw + pg * 8 * 128;  // block-uniform rows
  const unsigned short* r1 = X1kd + (b << 6) * 512 + d;
  const unsigned short* r2 = X2kd + (b << 6) * 512 + d;

  #pragma unroll 4
  for (int tt = 0; tt < 64; ++tt) {
    const float c = bf2f(r1[tt * 512]);
    #pragma unroll
    for (int pi = 0; pi < 8; ++pi) s[pi] += pwb[pi * 128 + tt] * c;
  }
  #pragma unroll 4
  for (int tt = 0; tt < 64; ++tt) {
    const float c = bf2f(r2[tt * 512]);
    #pragma unroll
    for (int pi = 0; pi < 8; ++pi) s[pi] += pwb[pi * 128 + 64 + tt] * c;
  }

  const int wv = d >> 6, ln = d & 63;
  float yv[8];
  #pragma unroll
  for (int pi = 0; pi < 8; ++pi) {
    const int p = pg * 8 + pi;
    const float y = x[((b << 6) + p) * 512 + d] + pb[p] + s[pi];
    yv[pi] = y;
    float sm = y, sq = y * y;
    #pragma unroll
    for (int off = 32; off > 0; off >>= 1) {
      sm += __shfl_xor(sm, off);
      sq += __shfl_xor(sq, off);
    }
    if (ln == 0) { red[pi * 16 + wv] = sm; red[pi * 16 + 8 + wv] = sq; }
  }
  __syncthreads();

  const float gam = gamma[d], bet = beta[d];
  #pragma unroll
  for (int pi = 0; pi < 8; ++pi) {
    float sum = 0.f, sumsq = 0.f;
    #pragma unroll
    for (int j = 0; j < 8; ++j) { sum += red[pi * 16 + j]; sumsq += red[pi * 16 + 8 + j]; }
    const float mu = sum * (1.f / 512.f);
    const float var = sumsq * (1.f / 512.f) - mu * mu;
    const float rs = rsqrtf(var + 1e-5f);
    const int p = pg * 8 + pi;
    out[((b << 6) + p) * 512 + d] = gam * (yv[pi] - mu) * rs + bet;
  }
}

extern "C" void kernel_launch(void* const* d_in, const int* in_sizes, int n_in,
                              void* d_out, int out_size, void* d_ws, size_t ws_size,
                              hipStream_t stream) {
  const float* x     = (const float*)d_in[0];
  const float* W1    = (const float*)d_in[1];
  const float* W2    = (const float*)d_in[2];
  const float* pw    = (const float*)d_in[3];
  const float* pb    = (const float*)d_in[4];
  const float* gamma = (const float*)d_in[5];
  const float* beta  = (const float*)d_in[6];
  float* out = (float*)d_out;

  char* ws = (char*)d_ws;
  unsigned short* X1kd = (unsigned short*)(ws);                          // 2MB [32][64][512]
  unsigned short* X2kd = (unsigned short*)(ws + (2u << 20));             // 2MB [32][64][512]
  unsigned short* W1t  = (unsigned short*)(ws + (4u << 20));             // 512KB swz
  unsigned short* W2t  = (unsigned short*)(ws + (4u << 20) + (512u << 10));

  transpose_w<<<dim3(128), dim3(256), 0, stream>>>(W1, W2, W1t, W2t);
  fused_layers<<<dim3(256), dim3(512), 107008, stream>>>(x, W1t, W2t, X1kd, X2kd);
  proj_ln<<<dim3(256), dim3(512), 0, stream>>>(x, X1kd, X2kd, pw, pb, gamma, beta, out);
}

// Round 12
// 54.528 us; speedup vs baseline: 1.2039x; 1.0216x over previous
//
#include <hip/hip_runtime.h>

typedef __attribute__((ext_vector_type(8))) short bf16x8;
typedef __attribute__((ext_vector_type(4))) float f32x4;
typedef __attribute__((ext_vector_type(8))) unsigned short u16x8;

__device__ __forceinline__ unsigned short f2bf(float f) {
  union { float f; unsigned u; } v; v.f = f;
  unsigned r = v.u + 0x7FFF + ((v.u >> 16) & 1);
  return (unsigned short)(r >> 16);
}
__device__ __forceinline__ float bf2f(unsigned short s) {
  union { unsigned u; float f; } v; v.u = ((unsigned)s) << 16;
  return v.f;
}
__device__ __forceinline__ void gll16(const unsigned short* g, unsigned short* l) {
  __builtin_amdgcn_global_load_lds(
      (const __attribute__((address_space(1))) void*)g,
      (__attribute__((address_space(3))) void*)l, 16, 0, 0);
}

// W[m][n][k] f32 -> Wt[m][k][n] bf16, 16B-chunk XOR swizzle: slot = g ^ (k&7)
__global__ __launch_bounds__(256) void transpose_w(const float* __restrict__ W1,
                                                   const float* __restrict__ W2,
                                                   unsigned short* __restrict__ W1t,
                                                   unsigned short* __restrict__ W2t) {
  __shared__ float ws_[64 * 64];
  const int m = blockIdx.x & 63, sel = blockIdx.x >> 6;
  const float* src = (sel ? W2 : W1) + m * 4096;
  unsigned short* dst = (sel ? W2t : W1t) + m * 4096;
  const int t = threadIdx.x;
  #pragma unroll
  for (int i = 0; i < 4; ++i) {
    const int idx = i * 256 + t;
    *(float4*)&ws_[idx << 2] = *(const float4*)&src[idx << 2];
  }
  __syncthreads();
  #pragma unroll
  for (int j = 0; j < 2; ++j) {
    const int idx = j * 256 + t;
    const int k = idx >> 3, g = idx & 7;
    u16x8 o;
    #pragma unroll
    for (int jj = 0; jj < 8; ++jj) o[jj] = f2bf(ws_[(((g << 3) + jj) << 6) + k]);
    const int slot = g ^ (k & 7);
    *(u16x8*)&dst[(k << 6) + (slot << 3)] = o;
  }
}

// One layer: 8 chunks of 8 m-slices (64KB) through a 2-buffer ping-pong.
// Per iter: issue chunk c+1 (8 gll16/thread) -> compute chunk c (8 m x 4 MFMA
// per wave ~1242 cyc/CU >= 64KB DMA issue-to-land) -> vmcnt(0) [only c+1's
// loads outstanding] -> s_barrier -> swap. Buffer c+1 overwrite is safe: its
// readers (chunk c-1) passed the barrier at end of iter c-1.
__device__ __forceinline__ void layer_pass(
    const unsigned short* __restrict__ Wt, unsigned short* wbuf,
    const unsigned short* u_lds, const bf16x8 (&Bf)[2][2],
    f32x4& acc0, f32x4& acc1,
    int aoff0, int aoff1, int uoff0, int uoff1, int t) {
  // prologue: chunk 0 -> buf0; the wait also drains older stores/loads, the
  // barrier publishes u_lds writes block-wide.
  #pragma unroll
  for (int j = 0; j < 8; ++j) gll16(Wt + j * 4096 + t * 8, wbuf + j * 4096 + t * 8);
  __builtin_amdgcn_sched_barrier(0);
  asm volatile("s_waitcnt vmcnt(0) lgkmcnt(0)" ::: "memory");
  __builtin_amdgcn_sched_barrier(0);
  __builtin_amdgcn_s_barrier();
  __builtin_amdgcn_sched_barrier(0);

  acc0 = (f32x4){0.f, 0.f, 0.f, 0.f};
  acc1 = (f32x4){0.f, 0.f, 0.f, 0.f};

  for (int c = 0; c < 8; ++c) {
    if (c < 7) {  // issue chunk c+1 into the other buffer
      const unsigned short* wsrc = Wt + (c + 1) * 32768;
      unsigned short* dst = wbuf + ((c + 1) & 1) * 32768;
      #pragma unroll
      for (int j = 0; j < 8; ++j) gll16(wsrc + j * 4096 + t * 8, dst + j * 4096 + t * 8);
    }
    const unsigned short* bufc = wbuf + (c & 1) * 32768;
    #pragma unroll
    for (int mm = 0; mm < 8; ++mm) {
      const int m = (c << 3) + mm;
      bf16x8 a0 = *(const bf16x8*)(bufc + mm * 4096 + aoff0);
      bf16x8 a1 = *(const bf16x8*)(bufc + mm * 4096 + aoff1);
      f32x4 t0 = {0.f, 0.f, 0.f, 0.f}, t1 = {0.f, 0.f, 0.f, 0.f};
      t0 = __builtin_amdgcn_mfma_f32_16x16x32_bf16(a0, Bf[0][0], t0, 0, 0, 0);
      t0 = __builtin_amdgcn_mfma_f32_16x16x32_bf16(a1, Bf[0][1], t0, 0, 0, 0);
      t1 = __builtin_amdgcn_mfma_f32_16x16x32_bf16(a0, Bf[1][0], t1, 0, 0, 0);
      t1 = __builtin_amdgcn_mfma_f32_16x16x32_bf16(a1, Bf[1][1], t1, 0, 0, 0);
      const float u0 = bf2f(u_lds[m * 64 + uoff0]);
      const float u1 = bf2f(u_lds[m * 64 + uoff1]);
      #pragma unroll
      for (int r = 0; r < 4; ++r) {
        acc0[r] += u0 * t0[r];
        acc1[r] += u1 * t1[r];
      }
    }
    if (c < 7) {
      __builtin_amdgcn_sched_barrier(0);
      asm volatile("s_waitcnt vmcnt(0)" ::: "memory");  // chunk c+1 landed
      __builtin_amdgcn_sched_barrier(0);
      __builtin_amdgcn_s_barrier();
      __builtin_amdgcn_sched_barrier(0);
    }
  }
  __syncthreads();  // all waves done with wbuf + u_lds before epilogue rewrites
}

// Fused cross layers. Block = (b, 64-d tile); 256 blocks, 512 threads
// = 8 waves = 4 kt x 2 dh. Dynamic LDS: wbuf[2][64KB] | u_lds[64][64] = 139264 B
__global__ __launch_bounds__(512) void fused_layers(
    const float* __restrict__ x,
    const unsigned short* __restrict__ W1t, const unsigned short* __restrict__ W2t,
    unsigned short* __restrict__ X1kd, unsigned short* __restrict__ X2kd) {
  extern __shared__ char smem[];
  unsigned short* wbuf = (unsigned short*)smem;               // 2*32768 shorts
  unsigned short* u_lds = (unsigned short*)(smem + 131072);   // [m][64]

  const int t = threadIdx.x;
  const int l = t & 63, w = t >> 6;
  const int kt = w & 3, dh = w >> 2;
  const int b = blockIdx.x >> 3, d0 = (blockIdx.x & 7) << 6;
  const int l15 = l & 15, lg = l >> 4;

  // stage u1 = bf16(x[b, m, d-tile]) -> u_lds[m][dl]
  {
    const int m = t >> 3, ch = t & 7;
    const float* src = x + ((b << 6) + m) * 512 + d0 + (ch << 3);
    float4 a = *(const float4*)src;
    float4 c4 = *(const float4*)(src + 4);
    u16x8 o;
    o[0] = f2bf(a.x); o[1] = f2bf(a.y); o[2] = f2bf(a.z); o[3] = f2bf(a.w);
    o[4] = f2bf(c4.x); o[5] = f2bf(c4.y); o[6] = f2bf(c4.z); o[7] = f2bf(c4.w);
    *(u16x8*)&u_lds[(m << 6) + (ch << 3)] = o;
  }

  // B fragments from x (V = X0 both layers)
  bf16x8 Bf[2][2];
  {
    const float* xb = x + (b << 6) * 512 + d0 + dh * 32 + l15;
    #pragma unroll
    for (int dt = 0; dt < 2; ++dt)
      #pragma unroll
      for (int h = 0; h < 2; ++h) {
        bf16x8 o;
        #pragma unroll
        for (int jj = 0; jj < 8; ++jj)
          o[jj] = (short)f2bf(xb[(h * 32 + lg * 8 + jj) * 512 + dt * 16]);
        Bf[dt][h] = o;
      }
  }

  const int krow = kt * 16 + l15;
  const int kx = krow & 7;
  const int aoff0 = krow * 64 + ((0 + lg) ^ kx) * 8;
  const int aoff1 = krow * 64 + ((4 + lg) ^ kx) * 8;
  const int uoff0 = dh * 32 + l15;
  const int uoff1 = dh * 32 + 16 + l15;

  f32x4 acc0, acc1;

  // ---- layer 1 ----
  layer_pass(W1t, wbuf, u_lds, Bf, acc0, acc1, aoff0, aoff1, uoff0, uoff1, t);

  // epilogue 1: relu -> X1kd (global) AND u_lds (layer-2 u).
  #pragma unroll
  for (int dt = 0; dt < 2; ++dt) {
    const f32x4 a = dt ? acc1 : acc0;
    #pragma unroll
    for (int r = 0; r < 4; ++r) {
      const int k = kt * 16 + lg * 4 + r;
      const int dl = dh * 32 + dt * 16 + l15;
      const unsigned short hv = f2bf(fmaxf(a[r], 0.f));
      X1kd[((b << 6) + k) * 512 + d0 + dl] = hv;
      u_lds[k * 64 + dl] = hv;
    }
  }
  // layer-2 prologue waits vmcnt(0) lgkmcnt(0) + barrier: drains the stores
  // and makes the u_lds writes visible block-wide before compute.

  // ---- layer 2 ----
  layer_pass(W2t, wbuf, u_lds, Bf, acc0, acc1, aoff0, aoff1, uoff0, uoff1, t);

  // epilogue 2
  #pragma unroll
  for (int dt = 0; dt < 2; ++dt) {
    const f32x4 a = dt ? acc1 : acc0;
    #pragma unroll
    for (int r = 0; r < 4; ++r) {
      const int k = kt * 16 + lg * 4 + r;
      const int dl = dh * 32 + dt * 16 + l15;
      X2kd[((b << 6) + k) * 512 + d0 + dl] = f2bf(fmaxf(a[r], 0.f));
    }
  }
}

// out[b,p,d] = LN_d( x[b,p,d] + pb[p] + sum_t pw[p,t]*X1kd[b][t][d] + pw[p,64+t]*X2kd[b][t][d] )
// grid 256 = (b, 8-p group); 512 threads = d.
__global__ __launch_bounds__(512) void proj_ln(
    const float* __restrict__ x, const unsigned short* __restrict__ X1kd,
    const unsigned short* __restrict__ X2kd, const float* __restrict__ pw,
    const float* __restrict__ pb, const float* __restrict__ gamma,
    const float* __restrict__ beta, float* __restrict__ out) {
  const int b = blockIdx.x >> 3, pg = blockIdx.x & 7;
  const int d = threadIdx.x;
  __shared__ float red[8 * 16];

  float s[8] = {0.f, 0.f, 0.f, 0.f, 0.f, 0.f, 0.f, 0.f};
  const float* pwb = pw + pg * 8 * 128;  // block-uniform rows
  const unsigned short* r1 = X1kd + (b << 6) * 512 + d;
  const unsigned short* r2 = X2kd + (b << 6) * 512 + d;

  #pragma unroll 4
  for (int tt = 0; tt < 64; ++tt) {
    const float c = bf2f(r1[tt * 512]);
    #pragma unroll
    for (int pi = 0; pi < 8; ++pi) s[pi] += pwb[pi * 128 + tt] * c;
  }
  #pragma unroll 4
  for (int tt = 0; tt < 64; ++tt) {
    const float c = bf2f(r2[tt * 512]);
    #pragma unroll
    for (int pi = 0; pi < 8; ++pi) s[pi] += pwb[pi * 128 + 64 + tt] * c;
  }

  const int wv = d >> 6, ln = d & 63;
  float yv[8];
  #pragma unroll
  for (int pi = 0; pi < 8; ++pi) {
    const int p = pg * 8 + pi;
    const float y = x[((b << 6) + p) * 512 + d] + pb[p] + s[pi];
    yv[pi] = y;
    float sm = y, sq = y * y;
    #pragma unroll
    for (int off = 32; off > 0; off >>= 1) {
      sm += __shfl_xor(sm, off);
      sq += __shfl_xor(sq, off);
    }
    if (ln == 0) { red[pi * 16 + wv] = sm; red[pi * 16 + 8 + wv] = sq; }
  }
  __syncthreads();

  const float gam = gamma[d], bet = beta[d];
  #pragma unroll
  for (int pi = 0; pi < 8; ++pi) {
    float sum = 0.f, sumsq = 0.f;
    #pragma unroll
    for (int j = 0; j < 8; ++j) { sum += red[pi * 16 + j]; sumsq += red[pi * 16 + 8 + j]; }
    const float mu = sum * (1.f / 512.f);
    const float var = sumsq * (1.f / 512.f) - mu * mu;
    const float rs = rsqrtf(var + 1e-5f);
    const int p = pg * 8 + pi;
    out[((b << 6) + p) * 512 + d] = gam * (yv[pi] - mu) * rs + bet;
  }
}

extern "C" void kernel_launch(void* const* d_in, const int* in_sizes, int n_in,
                              void* d_out, int out_size, void* d_ws, size_t ws_size,
                              hipStream_t stream) {
  const float* x     = (const float*)d_in[0];
  const float* W1    = (const float*)d_in[1];
  const float* W2    = (const float*)d_in[2];
  const float* pw    = (const float*)d_in[3];
  const float* pb    = (const float*)d_in[4];
  const float* gamma = (const float*)d_in[5];
  const float* beta  = (const float*)d_in[6];
  float* out = (float*)d_out;

  char* ws = (char*)d_ws;
  unsigned short* X1kd = (unsigned short*)(ws);                          // 2MB [32][64][512]
  unsigned short* X2kd = (unsigned short*)(ws + (2u << 20));             // 2MB [32][64][512]
  unsigned short* W1t  = (unsigned short*)(ws + (4u << 20));             // 512KB swz
  unsigned short* W2t  = (unsigned short*)(ws + (4u << 20) + (512u << 10));

  transpose_w<<<dim3(128), dim3(256), 0, stream>>>(W1, W2, W1t, W2t);
  fused_layers<<<dim3(256), dim3(512), 139264, stream>>>(x, W1t, W2t, X1kd, X2kd);
  proj_ln<<<dim3(256), dim3(512), 0, stream>>>(x, X1kd, X2kd, pw, pb, gamma, beta, out);
}